// Round 6
// baseline (168.852 us; speedup 1.0000x reference)
//
#include <hip/hip_runtime.h>
#include <stdint.h>

#define Bq 4
#define Sq 4096
#define DIN 512
#define Uq 128
#define Mq (Bq * Sq)
#define LOG2E 1.44269504f

typedef __attribute__((ext_vector_type(8))) _Float16 f16x8;
typedef __attribute__((ext_vector_type(4))) float f32x4;
typedef unsigned short u16;

__device__ __forceinline__ u16 f2h(float f) {
  union { _Float16 h; u16 u; } v;
  v.h = (_Float16)f;
  return v.u;
}
__device__ __forceinline__ unsigned pk2(float a, float b) {
  return __builtin_bit_cast(unsigned, __builtin_amdgcn_cvt_pkrtz(a, b));
}
__device__ __forceinline__ void gl_lds16(const void* g, void* l) {
  __builtin_amdgcn_global_load_lds(
      (const __attribute__((address_space(1))) unsigned int*)g,
      (__attribute__((address_space(3))) unsigned int*)l, 16, 0, 0);
}

// ---------------- W transpose: W[512][128] f32 -> Wt[128][512] fp16 ----------------
__global__ __launch_bounds__(256) void wt_kernel(const float* __restrict__ Wqp,
                                                 const float* __restrict__ Wkp,
                                                 const float* __restrict__ Wvp,
                                                 u16* __restrict__ wt) {
  int idx = blockIdx.x * 256 + threadIdx.x;
  int z = idx >> 16, r = idx & 65535;
  int n = r >> 9, k = r & 511;
  const float* W = (z == 0) ? Wqp : ((z == 1) ? Wkp : Wvp);
  wt[idx] = f2h(W[k * Uq + n]);
}

// ------------- fused QKV projection + ReLU -> fp16 (q scaled by log2e) -------------
// 64-row tiles, 256 threads; launch_bounds(256,3) caps VGPR at 170 (acc[3][8]=96 fits).
__global__ __launch_bounds__(256, 3) void proj_kernel(const float* __restrict__ X,
                                                      const u16* __restrict__ Wt,
                                                      const float* __restrict__ bqp,
                                                      const float* __restrict__ bkp,
                                                      const float* __restrict__ bvp,
                                                      u16* __restrict__ qkv) {
  const int mbase = blockIdx.x * 64;
  const int tid = threadIdx.x;
  const int wid = tid >> 6, lane = tid & 63;
  const int lo = lane & 15, g = lane >> 4;

  __shared__ __align__(16) u16 xt[64][40];

  f32x4 acc[3][8];
#pragma unroll
  for (int z = 0; z < 3; ++z)
#pragma unroll
    for (int f = 0; f < 8; ++f) acc[z][f] = (f32x4){0.f, 0.f, 0.f, 0.f};

  const int row = tid >> 2, cc = (tid & 3) * 8;
  const float* xsrc = X + (size_t)(mbase + row) * DIN + cc;
  float4 nv0 = *(const float4*)xsrc;
  float4 nv1 = *(const float4*)(xsrc + 4);
  const u16* wbase = Wt + (size_t)lo * 512 + 8 * g;

  for (int step = 0; step < 16; ++step) {
    {
      union { u16 u[8]; uint4 v; } pk;
      pk.u[0] = f2h(nv0.x); pk.u[1] = f2h(nv0.y); pk.u[2] = f2h(nv0.z); pk.u[3] = f2h(nv0.w);
      pk.u[4] = f2h(nv1.x); pk.u[5] = f2h(nv1.y); pk.u[6] = f2h(nv1.z); pk.u[7] = f2h(nv1.w);
      *(uint4*)(&xt[row][cc]) = pk.v;
    }
    __syncthreads();
    if (step < 15) {
      const float* s2 = xsrc + (step + 1) * 32;
      nv0 = *(const float4*)s2;
      nv1 = *(const float4*)(s2 + 4);
    }
    f16x8 a = *(const f16x8*)(&xt[16 * wid + lo][8 * g]);
#pragma unroll
    for (int z = 0; z < 3; ++z)
#pragma unroll
      for (int f = 0; f < 8; ++f) {
        f16x8 bfr = *(const f16x8*)(wbase + z * 65536 + f * 8192 + step * 32);
        acc[z][f] = __builtin_amdgcn_mfma_f32_16x16x32_f16(a, bfr, acc[z][f], 0, 0, 0);
      }
    __syncthreads();
  }

#pragma unroll
  for (int z = 0; z < 3; ++z) {
    const float* bias = (z == 0) ? bqp : ((z == 1) ? bkp : bvp);
    if (z < 2) {
      u16* dst = qkv + (size_t)z * Mq * Uq;
      const float qs = (z == 0) ? LOG2E : 1.0f;   // q pre-scaled into log2 domain
#pragma unroll
      for (int f = 0; f < 8; ++f) {
        const int n = 16 * f + lo;
        const float bb = bias[n];
#pragma unroll
        for (int r = 0; r < 4; ++r) {
          const int m = mbase + 16 * wid + 4 * g + r;
          dst[(size_t)m * Uq + n] = f2h(fmaxf(acc[z][f][r] + bb, 0.f) * qs);
        }
      }
    } else {
      u16* vT = qkv + (size_t)2 * Mq * Uq;   // vT[batch][n][s]
      const int m0 = mbase + 16 * wid + 4 * g;
      const int bb_ = m0 >> 12, s0 = m0 & (Sq - 1);
#pragma unroll
      for (int f = 0; f < 8; ++f) {
        const int n = 16 * f + lo;
        const float bb = bias[n];
        ushort4 pv = make_ushort4(f2h(fmaxf(acc[z][f][0] + bb, 0.f)),
                                  f2h(fmaxf(acc[z][f][1] + bb, 0.f)),
                                  f2h(fmaxf(acc[z][f][2] + bb, 0.f)),
                                  f2h(fmaxf(acc[z][f][3] + bb, 0.f)));
        *(ushort4*)(vT + (size_t)bb_ * Uq * Sq + (size_t)n * Sq + s0) = pv;
      }
    }
  }
}

// ---------------- flash attention partials ----------------
// 4 waves x 16 q-rows; KBLK=64. LDS = kt 16K + vt 16K + plds 8K = 40KB.
// K: reg-staged single buffer (T14). V: gl_lds single buffer, issued post-B2.
__global__ __launch_bounds__(256, 3) void attn_kernel(const u16* __restrict__ qkv,
                                                      float* __restrict__ op,
                                                      float2* __restrict__ mlp,
                                                      int kvlen) {
  const int nb = gridDim.x;
  const int bid = blockIdx.x;
  const int xcd = bid & 7, idx = bid >> 3;
  const int b = xcd >> 1;
  const int within = (xcd & 1) * (nb >> 3) + idx;
  const int split = within >> 6, qblk = within & 63;
  const int kv0 = split * kvlen;
  const int nit = kvlen >> 6;

  const int tid = threadIdx.x;
  const int wid = tid >> 6, lane = tid & 63;
  const int lo = lane & 15, g = lane >> 4;

  const u16* kbase = qkv + (size_t)Mq * Uq + (size_t)b * Sq * Uq;
  const u16* vbase = qkv + (size_t)2 * Mq * Uq + (size_t)b * Uq * Sq;

  __shared__ __align__(16) unsigned char kt[16384];       // 64 x 256B, XOR-swizzled
  __shared__ __align__(16) unsigned char vt[16384];       // 128 x 128B, XOR-swizzled
  __shared__ __align__(16) unsigned char plds[4][2048];   // per-wave P, swizzled 128B rows

  // K reg-staging: wave w covers tile rows [16w,16w+16) = 4KB; lane -> 4 x 16B
  const int s4 = lane >> 4, j16 = lane & 15;
  const char* kg = (const char*)kbase + (size_t)(kv0 + 16 * wid) * 256 + 16 * lane;
  const int kwo0 = (16 * wid + 0 + s4) * 256 + ((j16 ^ ((0 + s4) & 7)) << 4);
  const int kwo1 = (16 * wid + 4 + s4) * 256 + ((j16 ^ ((4 + s4) & 7)) << 4);
  const int kwo2 = (16 * wid + 8 + s4) * 256 + ((j16 ^ ((8 + s4) & 7)) << 4);
  const int kwo3 = (16 * wid + 12 + s4) * 256 + ((j16 ^ ((12 + s4) & 7)) << 4);

  // V gl_lds: wave w covers vT rows [32w,32w+32); source pre-swizzled
  const int s8 = lane >> 3, j8 = lane & 7;
  const int vo = s8 * 8192 + ((j8 ^ s8) << 4);
  const char* vgp = (const char*)vbase + (size_t)kv0 * 2 + (size_t)wid * 262144 + vo;
  char* vl = (char*)vt + wid * 4096;

#define VSTAGE() do {                       \
    gl_lds16(vgp,          vl);             \
    gl_lds16(vgp + 65536,  vl + 1024);      \
    gl_lds16(vgp + 131072, vl + 2048);      \
    gl_lds16(vgp + 196608, vl + 3072);      \
  } while (0)

  // Q frags (B operand of swapped QK^T)
  const int qrow = b * Sq + qblk * 64 + wid * 16 + lo;
  f16x8 qf[4];
#pragma unroll
  for (int t = 0; t < 4; ++t)
    qf[t] = *(const f16x8*)(qkv + (size_t)qrow * Uq + 32 * t + 8 * g);

  // plds swizzled bases: row=lo (128B), chunk XOR (lo&7)
  char* const pl = (char*)plds;
  const int pbase = wid * 2048 + lo * 128;
  const int pw0 = pbase + (((g >> 1) ^ (lo & 7)) << 4) + 8 * (g & 1);
  const int pr0 = pbase + ((g ^ (lo & 7)) << 4);

  f32x4 acc[8];
#pragma unroll
  for (int f = 0; f < 8; ++f) acc[f] = (f32x4){0.f, 0.f, 0.f, 0.f};
  float m_run = -1e30f, l_run = 0.f;

  // ---- prologue: V(0) -> LDS, K(0) -> regs -> LDS, issue K(1) ----
  VSTAGE();
  uint4 ka0 = *(const uint4*)(kg + 0);
  uint4 ka1 = *(const uint4*)(kg + 1024);
  uint4 ka2 = *(const uint4*)(kg + 2048);
  uint4 ka3 = *(const uint4*)(kg + 3072);
  kg += 16384;
  asm volatile("s_waitcnt vmcnt(0)" ::: "memory");
  *(uint4*)(&kt[kwo0]) = ka0;
  *(uint4*)(&kt[kwo1]) = ka1;
  *(uint4*)(&kt[kwo2]) = ka2;
  *(uint4*)(&kt[kwo3]) = ka3;
  if (nit > 1) {
    ka0 = *(const uint4*)(kg + 0);
    ka1 = *(const uint4*)(kg + 1024);
    ka2 = *(const uint4*)(kg + 2048);
    ka3 = *(const uint4*)(kg + 3072);
    kg += 16384;
  }
  asm volatile("s_waitcnt lgkmcnt(0)" ::: "memory");
  __builtin_amdgcn_sched_barrier(0);
  __builtin_amdgcn_s_barrier();
  __builtin_amdgcn_sched_barrier(0);

  for (int it = 0; it < nit; ++it) {
    // ---- QK^T (swapped): lane owns q = lo, kv = 16h + 4g + r ----
    f32x4 sf[4];
    __builtin_amdgcn_s_setprio(1);
#pragma unroll
    for (int h = 0; h < 4; ++h) {
      sf[h] = (f32x4){0.f, 0.f, 0.f, 0.f};
      const int row = 16 * h + lo;
#pragma unroll
      for (int t = 0; t < 4; ++t) {
        f16x8 a = *(const f16x8*)(&kt[row * 256 + ((64 * t + 16 * g) ^ ((lo & 7) << 4))]);
        sf[h] = __builtin_amdgcn_mfma_f32_16x16x32_f16(a, qf[t], sf[h], 0, 0, 0);
      }
    }
    __builtin_amdgcn_s_setprio(0);

    // ---- online softmax (log2 domain; q pre-scaled by log2e) ----
    float tmax = -1e30f;
#pragma unroll
    for (int h = 0; h < 4; ++h)
#pragma unroll
      for (int r = 0; r < 4; ++r) tmax = fmaxf(tmax, sf[h][r]);
    tmax = fmaxf(tmax, __shfl_xor(tmax, 16));
    tmax = fmaxf(tmax, __shfl_xor(tmax, 32));

    if (__any(tmax > m_run + 8.f)) {        // T13 defer-max: P bounded by 2^8
      const float m_new = fmaxf(m_run, tmax);
      const float scale = exp2f(m_run - m_new);
#pragma unroll
      for (int r = 0; r < 4; ++r) {
        const float sc = __shfl(scale, 4 * g + r);
#pragma unroll
        for (int f = 0; f < 8; ++f) acc[f][r] *= sc;
      }
      l_run *= scale;
      m_run = m_new;
    }

    float psum = 0.f;
    float p[16];
#pragma unroll
    for (int h = 0; h < 4; ++h)
#pragma unroll
      for (int r = 0; r < 4; ++r) {
        const float pv = exp2f(sf[h][r] - m_run);
        psum += pv;
        p[4 * h + r] = pv;
      }
    psum += __shfl_xor(psum, 16);
    psum += __shfl_xor(psum, 32);
    l_run += psum;

    // ---- P -> fp16 pairs -> swizzled plds (per-wave, no barrier) ----
#pragma unroll
    for (int h = 0; h < 4; ++h) {
      uint2 pq = make_uint2(pk2(p[4 * h + 0], p[4 * h + 1]),
                            pk2(p[4 * h + 2], p[4 * h + 3]));
      *(uint2*)(pl + (pw0 ^ (h << 5))) = pq;
    }

    asm volatile("s_waitcnt vmcnt(0)" ::: "memory");   // V(it) landed (K long done)
    __builtin_amdgcn_sched_barrier(0);
    __builtin_amdgcn_s_barrier();                      // B1: V visible, kt QK reads done
    __builtin_amdgcn_sched_barrier(0);

    // ---- PV: acc[q=4g+r][n] += P[q][kv] * V[kv][n] ----
    __builtin_amdgcn_s_setprio(1);
#pragma unroll
    for (int s = 0; s < 2; ++s) {
      f16x8 pa = *(const f16x8*)(pl + (pr0 ^ (s << 6)));
#pragma unroll
      for (int f = 0; f < 8; ++f) {
        const int n = 16 * f + lo;
        f16x8 bv = *(const f16x8*)(&vt[n * 128 + ((64 * s + 16 * g) ^ ((lo & 7) << 4))]);
        acc[f] = __builtin_amdgcn_mfma_f32_16x16x32_f16(pa, bv, acc[f], 0, 0, 0);
      }
    }
    __builtin_amdgcn_s_setprio(0);

    if (it + 1 < nit) {                    // K(it+1): regs -> kt (auto vmcnt wait)
      *(uint4*)(&kt[kwo0]) = ka0;
      *(uint4*)(&kt[kwo1]) = ka1;
      *(uint4*)(&kt[kwo2]) = ka2;
      *(uint4*)(&kt[kwo3]) = ka3;
    }
    asm volatile("s_waitcnt lgkmcnt(0)" ::: "memory");
    __builtin_amdgcn_sched_barrier(0);
    __builtin_amdgcn_s_barrier();          // B2: kt(it+1) visible, vt PV reads done
    __builtin_amdgcn_sched_barrier(0);

    if (it + 1 < nit) {
      vgp += 128;
      VSTAGE();                            // V(it+1) flies under next QK^T+softmax
      if (it + 2 < nit) {
        ka0 = *(const uint4*)(kg + 0);
        ka1 = *(const uint4*)(kg + 1024);
        ka2 = *(const uint4*)(kg + 2048);
        ka3 = *(const uint4*)(kg + 3072);
        kg += 16384;
      }
    }
  }
#undef VSTAGE

  // ---- write unnormalized partials + (m,l) ----
  const size_t rb = (size_t)split * Mq + (size_t)b * Sq + qblk * 64 + wid * 16;
  if (g == 0) mlp[rb + lo] = make_float2(m_run, l_run);
  float* od = op + rb * Uq;
#pragma unroll
  for (int f = 0; f < 8; ++f) {
    const int n = 16 * f + lo;
#pragma unroll
    for (int r = 0; r < 4; ++r)
      od[(size_t)(4 * g + r) * Uq + n] = acc[f][r];
  }
}

// ---------------- combine kv-split partials (log2 domain) ----------------
__global__ __launch_bounds__(256) void combine_kernel(const float* __restrict__ op,
                                                      const float2* __restrict__ mlp,
                                                      float* __restrict__ out,
                                                      int nsplit) {
  const int idx = blockIdx.x * 256 + threadIdx.x;
  const int q = idx >> 5, nq = idx & 31;
  float M = -1e30f;
  for (int s = 0; s < nsplit; ++s) M = fmaxf(M, mlp[(size_t)s * Mq + q].x);
  float L = 0.f;
  float ox = 0.f, oy = 0.f, oz = 0.f, ow = 0.f;
  for (int s = 0; s < nsplit; ++s) {
    const float2 ml = mlp[(size_t)s * Mq + q];
    const float w = exp2f(ml.x - M);
    L += w * ml.y;
    const float4 v = *(const float4*)(op + ((size_t)s * Mq + q) * Uq + nq * 4);
    ox += w * v.x; oy += w * v.y; oz += w * v.z; ow += w * v.w;
  }
  const float inv = 1.f / L;
  *(float4*)(out + (size_t)q * Uq + nq * 4) = make_float4(ox * inv, oy * inv, oz * inv, ow * inv);
}

extern "C" void kernel_launch(void* const* d_in, const int* in_sizes, int n_in,
                              void* d_out, int out_size, void* d_ws, size_t ws_size,
                              hipStream_t stream) {
  const float* X   = (const float*)d_in[0];
  const float* Wqp = (const float*)d_in[1];
  const float* bqp = (const float*)d_in[2];
  const float* Wkp = (const float*)d_in[3];
  const float* bkp = (const float*)d_in[4];
  const float* Wvp = (const float*)d_in[5];
  const float* bvp = (const float*)d_in[6];
  float* out = (float*)d_out;

  u16* qkv = (u16*)d_ws;                                   // q(4MB) k(4MB) vT(4MB) fp16
  u16* wt  = qkv + (size_t)3 * Mq * Uq;                    // 3 x [128][512] fp16
  float* op = (float*)(wt + 3 * 65536);                    // partial O

  const size_t base = (size_t)12976128;
  const size_t per  = (size_t)8519680;
  int nsplit = 4;
  if (ws_size < base + 4 * per) nsplit = 2;
  if (ws_size < base + 2 * per) nsplit = 1;
  float2* mlp = (float2*)(op + (size_t)nsplit * Mq * Uq);

  wt_kernel<<<768, 256, 0, stream>>>(Wqp, Wkp, Wvp, wt);
  proj_kernel<<<Mq / 64, 256, 0, stream>>>(X, wt, bqp, bkp, bvp, qkv);
  attn_kernel<<<256 * nsplit, 256, 0, stream>>>(qkv, op, mlp, Sq / nsplit);
  combine_kernel<<<(Mq * 32) / 256, 256, 0, stream>>>(op, mlp, out, nsplit);
}

// Round 7
// 98.148 us; speedup vs baseline: 1.7204x; 1.7204x over previous
//
#include <hip/hip_runtime.h>
#include <stdint.h>

#define Bq 4
#define Sq 4096
#define DIN 512
#define Uq 128
#define Mq (Bq * Sq)
#define LOG2E 1.44269504f

typedef __attribute__((ext_vector_type(8))) _Float16 f16x8;
typedef __attribute__((ext_vector_type(4))) float f32x4;
typedef unsigned short u16;

__device__ __forceinline__ u16 f2h(float f) {
  union { _Float16 h; u16 u; } v;
  v.h = (_Float16)f;
  return v.u;
}
__device__ __forceinline__ unsigned pk2(float a, float b) {
  return __builtin_bit_cast(unsigned, __builtin_amdgcn_cvt_pkrtz(a, b));
}
__device__ __forceinline__ void gl_lds16(const void* g, void* l) {
  __builtin_amdgcn_global_load_lds(
      (const __attribute__((address_space(1))) unsigned int*)g,
      (__attribute__((address_space(3))) unsigned int*)l, 16, 0, 0);
}

// ---------------- W transpose: W[512][128] f32 -> Wt[128][512] fp16 ----------------
__global__ __launch_bounds__(256) void wt_kernel(const float* __restrict__ Wqp,
                                                 const float* __restrict__ Wkp,
                                                 const float* __restrict__ Wvp,
                                                 u16* __restrict__ wt) {
  int idx = blockIdx.x * 256 + threadIdx.x;
  int z = idx >> 16, r = idx & 65535;
  int n = r >> 9, k = r & 511;
  const float* W = (z == 0) ? Wqp : ((z == 1) ? Wkp : Wvp);
  wt[idx] = f2h(W[k * Uq + n]);
}

// ------------- fused QKV projection + ReLU -> fp16 (q scaled by log2e) -------------
// 32-row m-tiles, grid 512 (2 blocks/CU), 4 waves; wave w owns 6 global f-cols
// gf in [6w,6w+6) spanning q/k/v. B-frags reg-prefetched one step ahead.
__global__ __launch_bounds__(256, 2) void proj_kernel(const float* __restrict__ X,
                                                      const u16* __restrict__ Wt,
                                                      const float* __restrict__ bqp,
                                                      const float* __restrict__ bkp,
                                                      const float* __restrict__ bvp,
                                                      u16* __restrict__ qkv) {
  const int mbase = blockIdx.x * 32;
  const int tid = threadIdx.x;
  const int wid = tid >> 6, lane = tid & 63;
  const int lo = lane & 15, g = lane >> 4;

  __shared__ __align__(16) u16 xt[32][40];   // 32 rows x 32 fp16 (+pad to 80B rows)

  f32x4 acc[2][6];
#pragma unroll
  for (int mg = 0; mg < 2; ++mg)
#pragma unroll
    for (int fi = 0; fi < 6; ++fi) acc[mg][fi] = (f32x4){0.f, 0.f, 0.f, 0.f};

  // X staging: threads 0..127 each cover (row = tid>>2, 8 floats at (tid&3)*8)
  const int xrow = tid >> 2, xcc = (tid & 3) * 8;
  const float* xsrc = X + (size_t)(mbase + xrow) * DIN + xcc;
  float4 nv0, nv1;
  if (tid < 128) {
    nv0 = *(const float4*)xsrc;
    nv1 = *(const float4*)(xsrc + 4);
  }

  // B row pointers: gf = 6*wid + fi; Wt row = (gf>>3)*128 + (gf&7)*16 + lo
  const u16* wp[6];
#pragma unroll
  for (int fi = 0; fi < 6; ++fi) {
    const int gf = 6 * wid + fi;
    const int R = (gf >> 3) * 128 + (gf & 7) * 16 + lo;
    wp[fi] = Wt + (size_t)R * 512 + 8 * g;
  }
  f16x8 bw[6];
#pragma unroll
  for (int fi = 0; fi < 6; ++fi) bw[fi] = *(const f16x8*)(wp[fi]);

  for (int step = 0; step < 16; ++step) {
    if (tid < 128) {   // write staged X tile (fp16)
      union { u16 u[8]; uint4 v; } pk;
      pk.u[0] = f2h(nv0.x); pk.u[1] = f2h(nv0.y); pk.u[2] = f2h(nv0.z); pk.u[3] = f2h(nv0.w);
      pk.u[4] = f2h(nv1.x); pk.u[5] = f2h(nv1.y); pk.u[6] = f2h(nv1.z); pk.u[7] = f2h(nv1.w);
      *(uint4*)(&xt[xrow][xcc]) = pk.v;
    }
    __syncthreads();
    if (step < 15 && tid < 128) {   // prefetch next X tile into regs
      const float* s2 = xsrc + (step + 1) * 32;
      nv0 = *(const float4*)s2;
      nv1 = *(const float4*)(s2 + 4);
    }
    f16x8 a0 = *(const f16x8*)(&xt[lo][8 * g]);
    f16x8 a1 = *(const f16x8*)(&xt[16 + lo][8 * g]);
#pragma unroll
    for (int fi = 0; fi < 6; ++fi) {
      acc[0][fi] = __builtin_amdgcn_mfma_f32_16x16x32_f16(a0, bw[fi], acc[0][fi], 0, 0, 0);
      acc[1][fi] = __builtin_amdgcn_mfma_f32_16x16x32_f16(a1, bw[fi], acc[1][fi], 0, 0, 0);
    }
    if (step < 15) {   // prefetch next B-frags (land during barrier + staging)
#pragma unroll
      for (int fi = 0; fi < 6; ++fi)
        bw[fi] = *(const f16x8*)(wp[fi] + (step + 1) * 32);
    }
    __syncthreads();
  }

  // C/D layout: col (n-within-16) = lane&15, row (m) = 4*(lane>>4)+reg
#pragma unroll
  for (int fi = 0; fi < 6; ++fi) {
    const int gf = 6 * wid + fi;
    const int z = gf >> 3, fl = gf & 7;
    const float* bias = (z == 0) ? bqp : ((z == 1) ? bkp : bvp);
    const float bb = bias[fl * 16 + lo];
    if (z < 2) {
      u16* dst = qkv + (size_t)z * Mq * Uq;
      const float qs = (z == 0) ? LOG2E : 1.0f;
#pragma unroll
      for (int mg = 0; mg < 2; ++mg)
#pragma unroll
        for (int r = 0; r < 4; ++r) {
          const int m = mbase + 16 * mg + 4 * g + r;
          dst[(size_t)m * Uq + fl * 16 + lo] = f2h(fmaxf(acc[mg][fi][r] + bb, 0.f) * qs);
        }
    } else {
      u16* vT = qkv + (size_t)2 * Mq * Uq;   // vT[batch][n][s]
      const int n = fl * 16 + lo;
#pragma unroll
      for (int mg = 0; mg < 2; ++mg) {
        const int m0 = mbase + 16 * mg + 4 * g;
        const int bb_ = m0 >> 12, s0 = m0 & (Sq - 1);
        ushort4 pv = make_ushort4(f2h(fmaxf(acc[mg][fi][0] + bb, 0.f)),
                                  f2h(fmaxf(acc[mg][fi][1] + bb, 0.f)),
                                  f2h(fmaxf(acc[mg][fi][2] + bb, 0.f)),
                                  f2h(fmaxf(acc[mg][fi][3] + bb, 0.f)));
        *(ushort4*)(vT + (size_t)bb_ * Uq * Sq + (size_t)n * Sq + s0) = pv;
      }
    }
  }
}

// ---------------- flash attention partials ----------------
// 4 waves x 16 q-rows; KBLK=64. LDS = kt 16K + vt 16K + plds 8K = 40KB.
// K: reg-staged single buffer (T14). V: gl_lds single buffer, issued post-B2.
__global__ __launch_bounds__(256, 3) void attn_kernel(const u16* __restrict__ qkv,
                                                      float* __restrict__ op,
                                                      float2* __restrict__ mlp,
                                                      int kvlen) {
  const int nb = gridDim.x;
  const int bid = blockIdx.x;
  const int xcd = bid & 7, idx = bid >> 3;
  const int b = xcd >> 1;
  const int within = (xcd & 1) * (nb >> 3) + idx;
  const int split = within >> 6, qblk = within & 63;
  const int kv0 = split * kvlen;
  const int nit = kvlen >> 6;

  const int tid = threadIdx.x;
  const int wid = tid >> 6, lane = tid & 63;
  const int lo = lane & 15, g = lane >> 4;

  const u16* kbase = qkv + (size_t)Mq * Uq + (size_t)b * Sq * Uq;
  const u16* vbase = qkv + (size_t)2 * Mq * Uq + (size_t)b * Uq * Sq;

  __shared__ __align__(16) unsigned char kt[16384];       // 64 x 256B, XOR-swizzled
  __shared__ __align__(16) unsigned char vt[16384];       // 128 x 128B, XOR-swizzled
  __shared__ __align__(16) unsigned char plds[4][2048];   // per-wave P, swizzled rows

  // K reg-staging: wave w covers tile rows [16w,16w+16) = 4KB; lane -> 4 x 16B
  const int s4 = lane >> 4, j16 = lane & 15;
  const char* kg = (const char*)kbase + (size_t)(kv0 + 16 * wid) * 256 + 16 * lane;
  const int kwo0 = (16 * wid + 0 + s4) * 256 + ((j16 ^ ((0 + s4) & 7)) << 4);
  const int kwo1 = (16 * wid + 4 + s4) * 256 + ((j16 ^ ((4 + s4) & 7)) << 4);
  const int kwo2 = (16 * wid + 8 + s4) * 256 + ((j16 ^ ((8 + s4) & 7)) << 4);
  const int kwo3 = (16 * wid + 12 + s4) * 256 + ((j16 ^ ((12 + s4) & 7)) << 4);

  // V gl_lds: wave w covers vT rows [32w,32w+32); source pre-swizzled
  const int s8 = lane >> 3, j8 = lane & 7;
  const int vo = s8 * 8192 + ((j8 ^ s8) << 4);
  const char* vgp = (const char*)vbase + (size_t)kv0 * 2 + (size_t)wid * 262144 + vo;
  char* vl = (char*)vt + wid * 4096;

#define VSTAGE() do {                       \
    gl_lds16(vgp,          vl);             \
    gl_lds16(vgp + 65536,  vl + 1024);      \
    gl_lds16(vgp + 131072, vl + 2048);      \
    gl_lds16(vgp + 196608, vl + 3072);      \
  } while (0)

  // Q frags (B operand of swapped QK^T)
  const int qrow = b * Sq + qblk * 64 + wid * 16 + lo;
  f16x8 qf[4];
#pragma unroll
  for (int t = 0; t < 4; ++t)
    qf[t] = *(const f16x8*)(qkv + (size_t)qrow * Uq + 32 * t + 8 * g);

  // plds swizzled bases: row=lo (128B), chunk XOR (lo&7)
  char* const pl = (char*)plds;
  const int pbase = wid * 2048 + lo * 128;
  const int pw0 = pbase + (((g >> 1) ^ (lo & 7)) << 4) + 8 * (g & 1);
  const int pr0 = pbase + ((g ^ (lo & 7)) << 4);

  f32x4 acc[8];
#pragma unroll
  for (int f = 0; f < 8; ++f) acc[f] = (f32x4){0.f, 0.f, 0.f, 0.f};
  float m_run = -1e30f, l_run = 0.f;

  // ---- prologue: V(0) -> LDS, K(0) -> regs -> LDS, issue K(1) ----
  VSTAGE();
  uint4 ka0 = *(const uint4*)(kg + 0);
  uint4 ka1 = *(const uint4*)(kg + 1024);
  uint4 ka2 = *(const uint4*)(kg + 2048);
  uint4 ka3 = *(const uint4*)(kg + 3072);
  kg += 16384;
  asm volatile("s_waitcnt vmcnt(0)" ::: "memory");
  *(uint4*)(&kt[kwo0]) = ka0;
  *(uint4*)(&kt[kwo1]) = ka1;
  *(uint4*)(&kt[kwo2]) = ka2;
  *(uint4*)(&kt[kwo3]) = ka3;
  if (nit > 1) {
    ka0 = *(const uint4*)(kg + 0);
    ka1 = *(const uint4*)(kg + 1024);
    ka2 = *(const uint4*)(kg + 2048);
    ka3 = *(const uint4*)(kg + 3072);
    kg += 16384;
  }
  asm volatile("s_waitcnt lgkmcnt(0)" ::: "memory");
  __builtin_amdgcn_sched_barrier(0);
  __builtin_amdgcn_s_barrier();
  __builtin_amdgcn_sched_barrier(0);

  for (int it = 0; it < nit; ++it) {
    // ---- QK^T (swapped): lane owns q = lo, kv = 16h + 4g + r ----
    f32x4 sf[4];
    __builtin_amdgcn_s_setprio(1);
#pragma unroll
    for (int h = 0; h < 4; ++h) {
      sf[h] = (f32x4){0.f, 0.f, 0.f, 0.f};
      const int row = 16 * h + lo;
#pragma unroll
      for (int t = 0; t < 4; ++t) {
        f16x8 a = *(const f16x8*)(&kt[row * 256 + ((64 * t + 16 * g) ^ ((lo & 7) << 4))]);
        sf[h] = __builtin_amdgcn_mfma_f32_16x16x32_f16(a, qf[t], sf[h], 0, 0, 0);
      }
    }
    __builtin_amdgcn_s_setprio(0);

    // ---- online softmax (log2 domain; q pre-scaled by log2e) ----
    float tmax = -1e30f;
#pragma unroll
    for (int h = 0; h < 4; ++h)
#pragma unroll
      for (int r = 0; r < 4; ++r) tmax = fmaxf(tmax, sf[h][r]);
    tmax = fmaxf(tmax, __shfl_xor(tmax, 16));
    tmax = fmaxf(tmax, __shfl_xor(tmax, 32));

    if (__any(tmax > m_run + 8.f)) {        // T13 defer-max: P bounded by 2^8
      const float m_new = fmaxf(m_run, tmax);
      const float scale = exp2f(m_run - m_new);
#pragma unroll
      for (int r = 0; r < 4; ++r) {
        const float sc = __shfl(scale, 4 * g + r);
#pragma unroll
        for (int f = 0; f < 8; ++f) acc[f][r] *= sc;
      }
      l_run *= scale;
      m_run = m_new;
    }

    float psum = 0.f;
    float p[16];
#pragma unroll
    for (int h = 0; h < 4; ++h)
#pragma unroll
      for (int r = 0; r < 4; ++r) {
        const float pv = exp2f(sf[h][r] - m_run);
        psum += pv;
        p[4 * h + r] = pv;
      }
    psum += __shfl_xor(psum, 16);
    psum += __shfl_xor(psum, 32);
    l_run += psum;

    // ---- P -> fp16 pairs -> swizzled plds (per-wave, no barrier) ----
#pragma unroll
    for (int h = 0; h < 4; ++h) {
      uint2 pq = make_uint2(pk2(p[4 * h + 0], p[4 * h + 1]),
                            pk2(p[4 * h + 2], p[4 * h + 3]));
      *(uint2*)(pl + (pw0 ^ (h << 5))) = pq;
    }

    asm volatile("s_waitcnt vmcnt(0)" ::: "memory");   // V(it) landed (K long done)
    __builtin_amdgcn_sched_barrier(0);
    __builtin_amdgcn_s_barrier();                      // B1: V visible, kt QK reads done
    __builtin_amdgcn_sched_barrier(0);

    // ---- PV: acc[q=4g+r][n] += P[q][kv] * V[kv][n] ----
    __builtin_amdgcn_s_setprio(1);
#pragma unroll
    for (int s = 0; s < 2; ++s) {
      f16x8 pa = *(const f16x8*)(pl + (pr0 ^ (s << 6)));
#pragma unroll
      for (int f = 0; f < 8; ++f) {
        const int n = 16 * f + lo;
        f16x8 bv = *(const f16x8*)(&vt[n * 128 + ((64 * s + 16 * g) ^ ((lo & 7) << 4))]);
        acc[f] = __builtin_amdgcn_mfma_f32_16x16x32_f16(pa, bv, acc[f], 0, 0, 0);
      }
    }
    __builtin_amdgcn_s_setprio(0);

    if (it + 1 < nit) {                    // K(it+1): regs -> kt
      *(uint4*)(&kt[kwo0]) = ka0;
      *(uint4*)(&kt[kwo1]) = ka1;
      *(uint4*)(&kt[kwo2]) = ka2;
      *(uint4*)(&kt[kwo3]) = ka3;
    }
    asm volatile("s_waitcnt lgkmcnt(0)" ::: "memory");
    __builtin_amdgcn_sched_barrier(0);
    __builtin_amdgcn_s_barrier();          // B2: kt(it+1) visible, vt PV reads done
    __builtin_amdgcn_sched_barrier(0);

    if (it + 1 < nit) {
      vgp += 128;
      VSTAGE();                            // V(it+1) flies under next QK^T+softmax
      if (it + 2 < nit) {
        ka0 = *(const uint4*)(kg + 0);
        ka1 = *(const uint4*)(kg + 1024);
        ka2 = *(const uint4*)(kg + 2048);
        ka3 = *(const uint4*)(kg + 3072);
        kg += 16384;
      }
    }
  }
#undef VSTAGE

  // ---- write unnormalized partials + (m,l) ----
  const size_t rb = (size_t)split * Mq + (size_t)b * Sq + qblk * 64 + wid * 16;
  if (g == 0) mlp[rb + lo] = make_float2(m_run, l_run);
  float* od = op + rb * Uq;
#pragma unroll
  for (int f = 0; f < 8; ++f) {
    const int n = 16 * f + lo;
#pragma unroll
    for (int r = 0; r < 4; ++r)
      od[(size_t)(4 * g + r) * Uq + n] = acc[f][r];
  }
}

// ---------------- combine kv-split partials (log2 domain) ----------------
__global__ __launch_bounds__(256) void combine_kernel(const float* __restrict__ op,
                                                      const float2* __restrict__ mlp,
                                                      float* __restrict__ out,
                                                      int nsplit) {
  const int idx = blockIdx.x * 256 + threadIdx.x;
  const int q = idx >> 5, nq = idx & 31;
  float M = -1e30f;
  for (int s = 0; s < nsplit; ++s) M = fmaxf(M, mlp[(size_t)s * Mq + q].x);
  float L = 0.f;
  float ox = 0.f, oy = 0.f, oz = 0.f, ow = 0.f;
  for (int s = 0; s < nsplit; ++s) {
    const float2 ml = mlp[(size_t)s * Mq + q];
    const float w = exp2f(ml.x - M);
    L += w * ml.y;
    const float4 v = *(const float4*)(op + ((size_t)s * Mq + q) * Uq + nq * 4);
    ox += w * v.x; oy += w * v.y; oz += w * v.z; ow += w * v.w;
  }
  const float inv = 1.f / L;
  *(float4*)(out + (size_t)q * Uq + nq * 4) = make_float4(ox * inv, oy * inv, oz * inv, ow * inv);
}

extern "C" void kernel_launch(void* const* d_in, const int* in_sizes, int n_in,
                              void* d_out, int out_size, void* d_ws, size_t ws_size,
                              hipStream_t stream) {
  const float* X   = (const float*)d_in[0];
  const float* Wqp = (const float*)d_in[1];
  const float* bqp = (const float*)d_in[2];
  const float* Wkp = (const float*)d_in[3];
  const float* bkp = (const float*)d_in[4];
  const float* Wvp = (const float*)d_in[5];
  const float* bvp = (const float*)d_in[6];
  float* out = (float*)d_out;

  u16* qkv = (u16*)d_ws;                                   // q(4MB) k(4MB) vT(4MB) fp16
  u16* wt  = qkv + (size_t)3 * Mq * Uq;                    // 3 x [128][512] fp16
  float* op = (float*)(wt + 3 * 65536);                    // partial O

  const size_t base = (size_t)12976128;
  const size_t per  = (size_t)8519680;
  int nsplit = 4;
  if (ws_size < base + 4 * per) nsplit = 2;
  if (ws_size < base + 2 * per) nsplit = 1;
  float2* mlp = (float2*)(op + (size_t)nsplit * Mq * Uq);

  wt_kernel<<<768, 256, 0, stream>>>(Wqp, Wkp, Wvp, wt);
  proj_kernel<<<Mq / 32, 256, 0, stream>>>(X, wt, bqp, bkp, bvp, qkv);
  attn_kernel<<<256 * nsplit, 256, 0, stream>>>(qkv, op, mlp, Sq / nsplit);
  combine_kernel<<<(Mq * 32) / 256, 256, 0, stream>>>(op, mlp, out, nsplit);
}

// Round 8
// 98.026 us; speedup vs baseline: 1.7225x; 1.0012x over previous
//
#include <hip/hip_runtime.h>
#include <stdint.h>

#define Bq 4
#define Sq 4096
#define DIN 512
#define Uq 128
#define Mq (Bq * Sq)
#define LOG2E 1.44269504f

typedef __attribute__((ext_vector_type(8))) _Float16 f16x8;
typedef __attribute__((ext_vector_type(4))) float f32x4;
typedef unsigned short u16;

__device__ __forceinline__ u16 f2h(float f) {
  union { _Float16 h; u16 u; } v;
  v.h = (_Float16)f;
  return v.u;
}
__device__ __forceinline__ unsigned pk2(float a, float b) {
  return __builtin_bit_cast(unsigned, __builtin_amdgcn_cvt_pkrtz(a, b));
}
__device__ __forceinline__ void gl_lds16(const void* g, void* l) {
  __builtin_amdgcn_global_load_lds(
      (const __attribute__((address_space(1))) unsigned int*)g,
      (__attribute__((address_space(3))) unsigned int*)l, 16, 0, 0);
}

// ---------------- W transpose: W[512][128] f32 -> Wt[128][512] fp16 ----------------
__global__ __launch_bounds__(256) void wt_kernel(const float* __restrict__ Wqp,
                                                 const float* __restrict__ Wkp,
                                                 const float* __restrict__ Wvp,
                                                 u16* __restrict__ wt) {
  int idx = blockIdx.x * 256 + threadIdx.x;
  int z = idx >> 16, r = idx & 65535;
  int n = r >> 9, k = r & 511;
  const float* W = (z == 0) ? Wqp : ((z == 1) ? Wkp : Wvp);
  wt[idx] = f2h(W[k * Uq + n]);
}

// ------------- fused QKV projection + ReLU -> fp16 (q scaled by log2e) -------------
// 32-row m-tiles, grid 512 (2 blocks/CU), 4 waves; wave w owns 6 global f-cols
// gf in [6w,6w+6) spanning q/k/v. B-frags reg-prefetched one step ahead.
__global__ __launch_bounds__(256, 2) void proj_kernel(const float* __restrict__ X,
                                                      const u16* __restrict__ Wt,
                                                      const float* __restrict__ bqp,
                                                      const float* __restrict__ bkp,
                                                      const float* __restrict__ bvp,
                                                      u16* __restrict__ qkv) {
  const int mbase = blockIdx.x * 32;
  const int tid = threadIdx.x;
  const int wid = tid >> 6, lane = tid & 63;
  const int lo = lane & 15, g = lane >> 4;

  __shared__ __align__(16) u16 xt[32][40];   // 32 rows x 32 fp16 (+pad to 80B rows)

  f32x4 acc[2][6];
#pragma unroll
  for (int mg = 0; mg < 2; ++mg)
#pragma unroll
    for (int fi = 0; fi < 6; ++fi) acc[mg][fi] = (f32x4){0.f, 0.f, 0.f, 0.f};

  const int xrow = tid >> 2, xcc = (tid & 3) * 8;
  const float* xsrc = X + (size_t)(mbase + xrow) * DIN + xcc;
  float4 nv0, nv1;
  if (tid < 128) {
    nv0 = *(const float4*)xsrc;
    nv1 = *(const float4*)(xsrc + 4);
  }

  const u16* wp[6];
#pragma unroll
  for (int fi = 0; fi < 6; ++fi) {
    const int gf = 6 * wid + fi;
    const int R = (gf >> 3) * 128 + (gf & 7) * 16 + lo;
    wp[fi] = Wt + (size_t)R * 512 + 8 * g;
  }
  f16x8 bw[6];
#pragma unroll
  for (int fi = 0; fi < 6; ++fi) bw[fi] = *(const f16x8*)(wp[fi]);

  for (int step = 0; step < 16; ++step) {
    if (tid < 128) {
      union { u16 u[8]; uint4 v; } pk;
      pk.u[0] = f2h(nv0.x); pk.u[1] = f2h(nv0.y); pk.u[2] = f2h(nv0.z); pk.u[3] = f2h(nv0.w);
      pk.u[4] = f2h(nv1.x); pk.u[5] = f2h(nv1.y); pk.u[6] = f2h(nv1.z); pk.u[7] = f2h(nv1.w);
      *(uint4*)(&xt[xrow][xcc]) = pk.v;
    }
    __syncthreads();
    if (step < 15 && tid < 128) {
      const float* s2 = xsrc + (step + 1) * 32;
      nv0 = *(const float4*)s2;
      nv1 = *(const float4*)(s2 + 4);
    }
    f16x8 a0 = *(const f16x8*)(&xt[lo][8 * g]);
    f16x8 a1 = *(const f16x8*)(&xt[16 + lo][8 * g]);
#pragma unroll
    for (int fi = 0; fi < 6; ++fi) {
      acc[0][fi] = __builtin_amdgcn_mfma_f32_16x16x32_f16(a0, bw[fi], acc[0][fi], 0, 0, 0);
      acc[1][fi] = __builtin_amdgcn_mfma_f32_16x16x32_f16(a1, bw[fi], acc[1][fi], 0, 0, 0);
    }
    if (step < 15) {
#pragma unroll
      for (int fi = 0; fi < 6; ++fi)
        bw[fi] = *(const f16x8*)(wp[fi] + (step + 1) * 32);
    }
    __syncthreads();
  }

#pragma unroll
  for (int fi = 0; fi < 6; ++fi) {
    const int gf = 6 * wid + fi;
    const int z = gf >> 3, fl = gf & 7;
    const float* bias = (z == 0) ? bqp : ((z == 1) ? bkp : bvp);
    const float bb = bias[fl * 16 + lo];
    if (z < 2) {
      u16* dst = qkv + (size_t)z * Mq * Uq;
      const float qs = (z == 0) ? LOG2E : 1.0f;
#pragma unroll
      for (int mg = 0; mg < 2; ++mg)
#pragma unroll
        for (int r = 0; r < 4; ++r) {
          const int m = mbase + 16 * mg + 4 * g + r;
          dst[(size_t)m * Uq + fl * 16 + lo] = f2h(fmaxf(acc[mg][fi][r] + bb, 0.f) * qs);
        }
    } else {
      u16* vT = qkv + (size_t)2 * Mq * Uq;   // vT[batch][n][s]
      const int n = fl * 16 + lo;
#pragma unroll
      for (int mg = 0; mg < 2; ++mg) {
        const int m0 = mbase + 16 * mg + 4 * g;
        const int bb_ = m0 >> 12, s0 = m0 & (Sq - 1);
        ushort4 pv = make_ushort4(f2h(fmaxf(acc[mg][fi][0] + bb, 0.f)),
                                  f2h(fmaxf(acc[mg][fi][1] + bb, 0.f)),
                                  f2h(fmaxf(acc[mg][fi][2] + bb, 0.f)),
                                  f2h(fmaxf(acc[mg][fi][3] + bb, 0.f)));
        *(ushort4*)(vT + (size_t)bb_ * Uq * Sq + (size_t)n * Sq + s0) = pv;
      }
    }
  }
}

// ---------------- flash attention partials ----------------
// 4 waves; each wave owns TWO 16-row q-sub-tiles (32 q-rows), block = 128 rows.
// KBLK=64. LDS = kt 16K + vt 16K + plds 16K = 48KB.
// K: reg-staged single buffer. V: gl_lds single buffer, issued post-B2.
__global__ __launch_bounds__(256, 2) void attn_kernel(const u16* __restrict__ qkv,
                                                      float* __restrict__ op,
                                                      float2* __restrict__ mlp,
                                                      int kvlen) {
  const int nb = gridDim.x;                  // 128 * nsplit
  const int bid = blockIdx.x;
  const int xcd = bid & 7, idx = bid >> 3;
  const int b = xcd >> 1;                    // batch pinned to 2 XCDs
  const int within = (xcd & 1) * (nb >> 3) + idx;   // [0, 32*nsplit)
  const int split = within >> 5, qblk = within & 31;
  const int kv0 = split * kvlen;
  const int nit = kvlen >> 6;

  const int tid = threadIdx.x;
  const int wid = tid >> 6, lane = tid & 63;
  const int lo = lane & 15, g = lane >> 4;

  const u16* kbase = qkv + (size_t)Mq * Uq + (size_t)b * Sq * Uq;
  const u16* vbase = qkv + (size_t)2 * Mq * Uq + (size_t)b * Uq * Sq;

  __shared__ __align__(16) unsigned char kt[16384];       // 64 x 256B, XOR-swizzled
  __shared__ __align__(16) unsigned char vt[16384];       // 128 x 128B, XOR-swizzled
  __shared__ __align__(16) unsigned char plds[4][4096];   // per-wave, 2 subs x 2KB

  // K reg-staging: wave w covers tile rows [16w,16w+16) = 4KB; lane -> 4 x 16B
  const int s4 = lane >> 4, j16 = lane & 15;
  const char* kg = (const char*)kbase + (size_t)(kv0 + 16 * wid) * 256 + 16 * lane;
  const int kwo0 = (16 * wid + 0 + s4) * 256 + ((j16 ^ ((0 + s4) & 7)) << 4);
  const int kwo1 = (16 * wid + 4 + s4) * 256 + ((j16 ^ ((4 + s4) & 7)) << 4);
  const int kwo2 = (16 * wid + 8 + s4) * 256 + ((j16 ^ ((8 + s4) & 7)) << 4);
  const int kwo3 = (16 * wid + 12 + s4) * 256 + ((j16 ^ ((12 + s4) & 7)) << 4);

  // V gl_lds: wave w covers vT rows [32w,32w+32); source pre-swizzled
  const int s8 = lane >> 3, j8 = lane & 7;
  const int vo = s8 * 8192 + ((j8 ^ s8) << 4);
  const char* vgp = (const char*)vbase + (size_t)kv0 * 2 + (size_t)wid * 262144 + vo;
  char* vl = (char*)vt + wid * 4096;

#define VSTAGE() do {                       \
    gl_lds16(vgp,          vl);             \
    gl_lds16(vgp + 65536,  vl + 1024);      \
    gl_lds16(vgp + 131072, vl + 2048);      \
    gl_lds16(vgp + 196608, vl + 3072);      \
  } while (0)

  // Q frags for both sub-tiles (B operand of swapped QK^T)
  const int qrow0 = b * Sq + qblk * 128 + wid * 32 + lo;
  f16x8 qf[2][4];
#pragma unroll
  for (int sq = 0; sq < 2; ++sq)
#pragma unroll
    for (int t = 0; t < 4; ++t)
      qf[sq][t] = *(const f16x8*)(qkv + (size_t)(qrow0 + 16 * sq) * Uq + 32 * t + 8 * g);

  // plds swizzled bases (within each 2KB sub-buffer)
  char* const pl = (char*)plds + wid * 4096;
  const int pw0 = lo * 128 + (((g >> 1) ^ (lo & 7)) << 4) + 8 * (g & 1);
  const int pr0 = lo * 128 + ((g ^ (lo & 7)) << 4);

  f32x4 acc[2][8];
#pragma unroll
  for (int sq = 0; sq < 2; ++sq)
#pragma unroll
    for (int f = 0; f < 8; ++f) acc[sq][f] = (f32x4){0.f, 0.f, 0.f, 0.f};
  float m_run[2] = {-1e30f, -1e30f}, l_run[2] = {0.f, 0.f};

  // ---- prologue: V(0) -> LDS, K(0) -> regs -> LDS, issue K(1) ----
  VSTAGE();
  uint4 ka0 = *(const uint4*)(kg + 0);
  uint4 ka1 = *(const uint4*)(kg + 1024);
  uint4 ka2 = *(const uint4*)(kg + 2048);
  uint4 ka3 = *(const uint4*)(kg + 3072);
  kg += 16384;
  asm volatile("s_waitcnt vmcnt(0)" ::: "memory");
  *(uint4*)(&kt[kwo0]) = ka0;
  *(uint4*)(&kt[kwo1]) = ka1;
  *(uint4*)(&kt[kwo2]) = ka2;
  *(uint4*)(&kt[kwo3]) = ka3;
  if (nit > 1) {
    ka0 = *(const uint4*)(kg + 0);
    ka1 = *(const uint4*)(kg + 1024);
    ka2 = *(const uint4*)(kg + 2048);
    ka3 = *(const uint4*)(kg + 3072);
    kg += 16384;
  }
  asm volatile("s_waitcnt lgkmcnt(0)" ::: "memory");
  __builtin_amdgcn_sched_barrier(0);
  __builtin_amdgcn_s_barrier();
  __builtin_amdgcn_sched_barrier(0);

  for (int it = 0; it < nit; ++it) {
    // ---- QK^T both subs: a-frag loaded once, used twice ----
    f32x4 sf[2][4];
    __builtin_amdgcn_s_setprio(1);
#pragma unroll
    for (int h = 0; h < 4; ++h) {
      sf[0][h] = (f32x4){0.f, 0.f, 0.f, 0.f};
      sf[1][h] = (f32x4){0.f, 0.f, 0.f, 0.f};
      const int row = 16 * h + lo;
#pragma unroll
      for (int t = 0; t < 4; ++t) {
        f16x8 a = *(const f16x8*)(&kt[row * 256 + ((64 * t + 16 * g) ^ ((lo & 7) << 4))]);
        sf[0][h] = __builtin_amdgcn_mfma_f32_16x16x32_f16(a, qf[0][t], sf[0][h], 0, 0, 0);
        sf[1][h] = __builtin_amdgcn_mfma_f32_16x16x32_f16(a, qf[1][t], sf[1][h], 0, 0, 0);
      }
    }
    __builtin_amdgcn_s_setprio(0);

    // ---- online softmax per sub (log2 domain; exp results stored in-place) ----
#pragma unroll
    for (int sq = 0; sq < 2; ++sq) {
      float tmax = -1e30f;
#pragma unroll
      for (int h = 0; h < 4; ++h)
#pragma unroll
        for (int r = 0; r < 4; ++r) tmax = fmaxf(tmax, sf[sq][h][r]);
      tmax = fmaxf(tmax, __shfl_xor(tmax, 16));
      tmax = fmaxf(tmax, __shfl_xor(tmax, 32));

      if (__any(tmax > m_run[sq] + 8.f)) {   // T13 defer-max
        const float m_new = fmaxf(m_run[sq], tmax);
        const float scale = exp2f(m_run[sq] - m_new);
#pragma unroll
        for (int r = 0; r < 4; ++r) {
          const float sc = __shfl(scale, 4 * g + r);
#pragma unroll
          for (int f = 0; f < 8; ++f) acc[sq][f][r] *= sc;
        }
        l_run[sq] *= scale;
        m_run[sq] = m_new;
      }

      float psum = 0.f;
#pragma unroll
      for (int h = 0; h < 4; ++h)
#pragma unroll
        for (int r = 0; r < 4; ++r) {
          const float pv = exp2f(sf[sq][h][r] - m_run[sq]);
          psum += pv;
          sf[sq][h][r] = pv;
        }
      psum += __shfl_xor(psum, 16);
      psum += __shfl_xor(psum, 32);
      l_run[sq] += psum;

#pragma unroll
      for (int h = 0; h < 4; ++h) {
        uint2 pq = make_uint2(pk2(sf[sq][h][0], sf[sq][h][1]),
                              pk2(sf[sq][h][2], sf[sq][h][3]));
        *(uint2*)(pl + sq * 2048 + (pw0 ^ (h << 5))) = pq;
      }
    }

    asm volatile("s_waitcnt vmcnt(0)" ::: "memory");   // V(it) landed
    __builtin_amdgcn_sched_barrier(0);
    __builtin_amdgcn_s_barrier();                      // B1
    __builtin_amdgcn_sched_barrier(0);

    // ---- PV both subs: bv loaded once, used twice ----
    __builtin_amdgcn_s_setprio(1);
#pragma unroll
    for (int ks = 0; ks < 2; ++ks) {
      f16x8 pa0 = *(const f16x8*)(pl + (pr0 ^ (ks << 6)));
      f16x8 pa1 = *(const f16x8*)(pl + 2048 + (pr0 ^ (ks << 6)));
#pragma unroll
      for (int f = 0; f < 8; ++f) {
        const int n = 16 * f + lo;
        f16x8 bv = *(const f16x8*)(&vt[n * 128 + ((64 * ks + 16 * g) ^ ((lo & 7) << 4))]);
        acc[0][f] = __builtin_amdgcn_mfma_f32_16x16x32_f16(pa0, bv, acc[0][f], 0, 0, 0);
        acc[1][f] = __builtin_amdgcn_mfma_f32_16x16x32_f16(pa1, bv, acc[1][f], 0, 0, 0);
      }
    }
    __builtin_amdgcn_s_setprio(0);

    if (it + 1 < nit) {                    // K(it+1): regs -> kt
      *(uint4*)(&kt[kwo0]) = ka0;
      *(uint4*)(&kt[kwo1]) = ka1;
      *(uint4*)(&kt[kwo2]) = ka2;
      *(uint4*)(&kt[kwo3]) = ka3;
    }
    asm volatile("s_waitcnt lgkmcnt(0)" ::: "memory");
    __builtin_amdgcn_sched_barrier(0);
    __builtin_amdgcn_s_barrier();          // B2
    __builtin_amdgcn_sched_barrier(0);

    if (it + 1 < nit) {
      vgp += 128;
      VSTAGE();                            // V(it+1) flies under next QK^T+softmax
      if (it + 2 < nit) {
        ka0 = *(const uint4*)(kg + 0);
        ka1 = *(const uint4*)(kg + 1024);
        ka2 = *(const uint4*)(kg + 2048);
        ka3 = *(const uint4*)(kg + 3072);
        kg += 16384;
      }
    }
  }
#undef VSTAGE

  // ---- write unnormalized partials + (m,l) per sub ----
#pragma unroll
  for (int sq = 0; sq < 2; ++sq) {
    const size_t rb = (size_t)split * Mq + (size_t)b * Sq + qblk * 128 + wid * 32 + sq * 16;
    if (g == 0) mlp[rb + lo] = make_float2(m_run[sq], l_run[sq]);
    float* od = op + rb * Uq;
#pragma unroll
    for (int f = 0; f < 8; ++f) {
      const int n = 16 * f + lo;
#pragma unroll
      for (int r = 0; r < 4; ++r)
        od[(size_t)(4 * g + r) * Uq + n] = acc[sq][f][r];
    }
  }
}

// ---------------- combine kv-split partials (log2 domain) ----------------
__global__ __launch_bounds__(256) void combine_kernel(const float* __restrict__ op,
                                                      const float2* __restrict__ mlp,
                                                      float* __restrict__ out,
                                                      int nsplit) {
  const int idx = blockIdx.x * 256 + threadIdx.x;
  const int q = idx >> 5, nq = idx & 31;
  float M = -1e30f;
  for (int s = 0; s < nsplit; ++s) M = fmaxf(M, mlp[(size_t)s * Mq + q].x);
  float L = 0.f;
  float ox = 0.f, oy = 0.f, oz = 0.f, ow = 0.f;
  for (int s = 0; s < nsplit; ++s) {
    const float2 ml = mlp[(size_t)s * Mq + q];
    const float w = exp2f(ml.x - M);
    L += w * ml.y;
    const float4 v = *(const float4*)(op + ((size_t)s * Mq + q) * Uq + nq * 4);
    ox += w * v.x; oy += w * v.y; oz += w * v.z; ow += w * v.w;
  }
  const float inv = 1.f / L;
  *(float4*)(out + (size_t)q * Uq + nq * 4) = make_float4(ox * inv, oy * inv, oz * inv, ow * inv);
}

extern "C" void kernel_launch(void* const* d_in, const int* in_sizes, int n_in,
                              void* d_out, int out_size, void* d_ws, size_t ws_size,
                              hipStream_t stream) {
  const float* X   = (const float*)d_in[0];
  const float* Wqp = (const float*)d_in[1];
  const float* bqp = (const float*)d_in[2];
  const float* Wkp = (const float*)d_in[3];
  const float* bkp = (const float*)d_in[4];
  const float* Wvp = (const float*)d_in[5];
  const float* bvp = (const float*)d_in[6];
  float* out = (float*)d_out;

  u16* qkv = (u16*)d_ws;                                   // q(4MB) k(4MB) vT(4MB) fp16
  u16* wt  = qkv + (size_t)3 * Mq * Uq;                    // 3 x [128][512] fp16
  float* op = (float*)(wt + 3 * 65536);                    // partial O

  const size_t base = (size_t)12976128;
  const size_t per  = (size_t)8519680;
  int nsplit = 4;
  if (ws_size < base + 4 * per) nsplit = 2;
  if (ws_size < base + 2 * per) nsplit = 1;
  float2* mlp = (float2*)(op + (size_t)nsplit * Mq * Uq);

  wt_kernel<<<768, 256, 0, stream>>>(Wqp, Wkp, Wvp, wt);
  proj_kernel<<<Mq / 32, 256, 0, stream>>>(X, wt, bqp, bkp, bvp, qkv);
  attn_kernel<<<128 * nsplit, 256, 0, stream>>>(qkv, op, mlp, Sq / nsplit);
  combine_kernel<<<(Mq * 32) / 256, 256, 0, stream>>>(op, mlp, out, nsplit);
}